// Round 16
// baseline (59.113 us; speedup 1.0000x reference)
//
#include <hip/hip_runtime.h>
#include <hip/hip_bf16.h>

#define BB 4
#define CC 256   // CQ == CVK == 256
#define LL 2048
#define HH 8
#define DD 32
#define EPSV 1e-5f

typedef __bf16 bf16x8 __attribute__((ext_vector_type(8)));
typedef __bf16 bf16x4 __attribute__((ext_vector_type(4)));
typedef __bf16 bf16x2 __attribute__((ext_vector_type(2)));
typedef float  f32x4  __attribute__((ext_vector_type(4)));
typedef float  f32x16 __attribute__((ext_vector_type(16)));
typedef unsigned int u32x4 __attribute__((ext_vector_type(4)));

static __device__ __forceinline__ unsigned pkbf(float lo, float hi) {
    bf16x2 p; p[0] = (__bf16)lo; p[1] = (__bf16)hi;
    return __builtin_bit_cast(unsigned, p);
}

// ---------------------------------------------------------------------------
// qkv gemm (round-6 verified): fp32 x + pe staged with in-LDS transpose+cast,
// fp32 weights BN-folded+cast during staging.  grid (16,4,12): z=which*4+b.
// block 512 (8 waves, 2Mx4N), tile 64 o x 128 l, K=256 (2 steps of 128).
// which<2 -> T-layout bf16 out via LDS transpose; which==2 -> natural bf16.
// ---------------------------------------------------------------------------
__global__ __launch_bounds__(512) void qkv_gemm_kernel(
    const float* __restrict__ qin, const float* __restrict__ kin,
    const float* __restrict__ vin,
    const float* __restrict__ peq, const float* __restrict__ pevk,
    const float* __restrict__ wq, const float* __restrict__ bq,
    const float* __restrict__ gq, const float* __restrict__ betaq,
    const float* __restrict__ mq, const float* __restrict__ varq,
    const float* __restrict__ wk, const float* __restrict__ bk,
    const float* __restrict__ gk, const float* __restrict__ betak,
    const float* __restrict__ mk, const float* __restrict__ vark,
    const float* __restrict__ wv, const float* __restrict__ bv,
    const float* __restrict__ gv, const float* __restrict__ betav,
    const float* __restrict__ mv, const float* __restrict__ varv,
    __bf16* __restrict__ qTo, __bf16* __restrict__ kTo, __bf16* __restrict__ vNo,
    float qscale)
{
    __shared__ __align__(16) __bf16 Wl[64][136];
    __shared__ __align__(16) __bf16 Xl[128][136];
    __bf16 (*Tl)[72] = (__bf16(*)[72])Xl;

    const int z = blockIdx.z;
    const int which = z >> 2;
    const int b = z & 3;
    const float* X    = which==0 ? qin : (which==1 ? kin : vin);
    const float* pe   = which==0 ? peq : pevk;
    const float* W    = which==0 ? wq  : (which==1 ? wk  : wv);
    const float* bia  = which==0 ? bq  : (which==1 ? bk  : bv);
    const float* gam  = which==0 ? gq  : (which==1 ? gk  : gv);
    const float* bet  = which==0 ? betaq : (which==1 ? betak : betav);
    const float* mea  = which==0 ? mq  : (which==1 ? mk  : mv);
    const float* var  = which==0 ? varq : (which==1 ? vark : varv);
    const float extra = (which==0) ? qscale : 1.0f;

    const int lt = blockIdx.x * 128;
    const int ot = blockIdx.y * 64;
    const int t  = threadIdx.x;
    const int wvi = t >> 6;
    const int wm = wvi >> 2;
    const int wn = wvi & 3;
    const int l  = t & 63;
    const int lq = l & 15;
    const int g  = l >> 4;

    f32x4 acc[2][2];
    #pragma unroll
    for (int mi = 0; mi < 2; ++mi)
        #pragma unroll
        for (int ni = 0; ni < 2; ++ni) acc[mi][ni] = (f32x4){0.f,0.f,0.f,0.f};

    for (int ks = 0; ks < 2; ++ks) {
        __syncthreads();
        #pragma unroll
        for (int i = 0; i < 4; ++i) {
            const int idx = i * 512 + t;
            const int row = idx >> 5;
            const int ch  = idx & 31;
            const int o   = ot + row;
            const float sc = gam[o] * rsqrtf(var[o] + EPSV) * extra;
            const float4 w4 = *(const float4*)&W[(size_t)o * CC + ks * 128 + ch * 4];
            bf16x4 wb;
            wb[0] = (__bf16)(w4.x * sc); wb[1] = (__bf16)(w4.y * sc);
            wb[2] = (__bf16)(w4.z * sc); wb[3] = (__bf16)(w4.w * sc);
            *(bf16x4*)&Wl[row][ch * 4] = wb;
        }
        #pragma unroll
        for (int i = 0; i < 2; ++i) {
            const int slot = i * 512 + t;
            const int lp = slot & 63;
            const int co = slot >> 6;
            const float* xp = &X[(size_t)(b * CC + ks * 128 + co * 8) * LL + lt + lp * 2];
            const float* pp = &pe[(size_t)(ks * 128 + co * 8) * LL + lt + lp * 2];
            bf16x8 lo, hi;
            #pragma unroll
            for (int j = 0; j < 8; ++j) {
                const float2 a = *(const float2*)&xp[(size_t)j * LL];
                const float2 p = *(const float2*)&pp[(size_t)j * LL];
                lo[j] = (__bf16)(a.x + p.x);
                hi[j] = (__bf16)(a.y + p.y);
            }
            *(bf16x8*)&Xl[lp * 2    ][co * 8] = lo;
            *(bf16x8*)&Xl[lp * 2 + 1][co * 8] = hi;
        }
        __syncthreads();

        #pragma unroll
        for (int kk = 0; kk < 4; ++kk) {
            bf16x8 af[2], bfr[2];
            #pragma unroll
            for (int mi = 0; mi < 2; ++mi)
                af[mi] = *(const bf16x8*)&Wl[wm * 32 + mi * 16 + lq][kk * 32 + g * 8];
            #pragma unroll
            for (int ni = 0; ni < 2; ++ni)
                bfr[ni] = *(const bf16x8*)&Xl[wn * 32 + ni * 16 + lq][kk * 32 + g * 8];
            #pragma unroll
            for (int mi = 0; mi < 2; ++mi)
                #pragma unroll
                for (int ni = 0; ni < 2; ++ni)
                    acc[mi][ni] = __builtin_amdgcn_mfma_f32_16x16x32_bf16(
                        af[mi], bfr[ni], acc[mi][ni], 0, 0, 0);
        }
    }

    float bb[2][4];
    #pragma unroll
    for (int mi = 0; mi < 2; ++mi) {
        const int o4 = ot + wm * 32 + mi * 16 + g * 4;
        const float4 b4 = *(const float4*)&bia[o4];
        const float4 g4 = *(const float4*)&gam[o4];
        const float4 v4 = *(const float4*)&var[o4];
        const float4 m4 = *(const float4*)&mea[o4];
        const float4 t4 = *(const float4*)&bet[o4];
        const float bs[4] = {b4.x,b4.y,b4.z,b4.w};
        const float gs[4] = {g4.x,g4.y,g4.z,g4.w};
        const float vs[4] = {v4.x,v4.y,v4.z,v4.w};
        const float ms[4] = {m4.x,m4.y,m4.z,m4.w};
        const float ts[4] = {t4.x,t4.y,t4.z,t4.w};
        #pragma unroll
        for (int r = 0; r < 4; ++r) {
            const float sc = gs[r] * rsqrtf(vs[r] + EPSV);
            bb[mi][r] = ((bs[r] - ms[r]) * sc + ts[r]) * extra;
        }
    }

    if (which < 2) {
        __bf16* outT = which==0 ? qTo : kTo;
        __syncthreads();
        #pragma unroll
        for (int mi = 0; mi < 2; ++mi) {
            #pragma unroll
            for (int ni = 0; ni < 2; ++ni) {
                bf16x4 pv;
                #pragma unroll
                for (int r = 0; r < 4; ++r) pv[r] = (__bf16)(acc[mi][ni][r] + bb[mi][r]);
                *(bf16x4*)&Tl[wn * 32 + ni * 16 + lq][wm * 32 + mi * 16 + g * 4] = pv;
            }
        }
        __syncthreads();
        #pragma unroll
        for (int i = 0; i < 2; ++i) {
            const int idx = i * 512 + t;
            const int lrow = idx >> 3, ch = idx & 7;
            *(bf16x8*)&outT[(size_t)(b * LL + lt + lrow) * CC + ot + ch * 8] =
                *(const bf16x8*)&Tl[lrow][ch * 8];
        }
    } else {
        #pragma unroll
        for (int mi = 0; mi < 2; ++mi) {
            #pragma unroll
            for (int ni = 0; ni < 2; ++ni) {
                const int col = lt + wn * 32 + ni * 16 + lq;
                #pragma unroll
                for (int r = 0; r < 4; ++r) {
                    const int o = ot + wm * 32 + mi * 16 + g * 4 + r;
                    vNo[(size_t)(b * CC + o) * LL + col] = (__bf16)(acc[mi][ni][r] + bb[mi][r]);
                }
            }
        }
    }
}

// ---------------------------------------------------------------------------
// attn (round-15 base + KV tile 256): 8 waves x 32 queries (256 q/block) over
// all 2048 keys; K/V tile of 256 keys double-buffered (LDS 64KB, 1 block/CU
// so VGPR cannot cap occupancy — round-8's failure mode is impossible here).
// Barriers halve to 8; depth-2 pipelined chunk rotation runs twice per tile.
// 32x32 MFMA, in-register softmax, XOR-swizzle, O0/O1 split, T4 lgkm-only
// barrier, XCD remap.  grid (8,8,4) = 256 blocks, block 512.
// ---------------------------------------------------------------------------
__global__ __launch_bounds__(512, 2) void attn_mfma_kernel(
    const __bf16* __restrict__ qT, const __bf16* __restrict__ kT,
    const __bf16* __restrict__ vN, __bf16* __restrict__ aT)
{
    __shared__ __align__(16) __bf16 KB[2][256 * 32];   // [key][d], slot-swizzled
    __shared__ __align__(16) __bf16 VB[2][32 * 256];   // [d][key], slot-swizzled

    // XCD remap: 256 blocks, 32 (b,h) groups (4/XCD), 8 q-blocks per group.
    const int flat = blockIdx.x + 8 * (blockIdx.y + 8 * blockIdx.z);
    const int xcd  = flat & 7;
    const int ixc  = flat >> 3;              // 0..31
    const int gidx = xcd + 8 * (ixc >> 3);   // 0..31 : (b,h) group
    const int qb   = ixc & 7;
    const int h    = gidx & 7;
    const int b    = gidx >> 3;

    const int t  = threadIdx.x;   // 0..511
    const int w  = t >> 6;        // 0..7
    const int l  = t & 63;
    const int lq = l & 31;
    const int hi = l >> 5;

    const int q0 = qb * 256 + w * 32;

    const __bf16* qrow = qT + ((size_t)(b * LL) + q0 + lq) * CC + h * DD;
    const bf16x8 qf0 = *(const bf16x8*)&qrow[hi * 8];
    const bf16x8 qf1 = *(const bf16x8*)&qrow[16 + hi * 8];

    const __bf16* kTb = kT + (size_t)(b * LL) * CC + h * DD;
    const __bf16* vNb = vN + ((size_t)(b * CC) + h * DD) * LL;

    // staging: 512 threads, 2 K slots + 2 V slots each (1024 slots per side).
    const int sk0 = t >> 2,        sp0 = t & 3;       // K: 256 keys x 4 chunks
    const int sk1 = 128 + (t >> 2), sp1 = t & 3;
    const int sd0 = t >> 5,        sv0 = t & 31;      // V: 32 d x 32 chunks
    const int sd1 = 16 + (t >> 5), sv1 = t & 31;
    const int kw0 = sk0 * 32 + (sp0 ^ ((sk0 >> 1) & 3)) * 8;
    const int kw1 = sk1 * 32 + (sp1 ^ ((sk1 >> 1) & 3)) * 8;
    const int vw0 = sd0 * 256 + (sv0 ^ (sd0 & 7)) * 8;
    const int vw1 = sd1 * 256 + (sv1 ^ (sd1 & 7)) * 8;

    bf16x8 kr0, kr1, vr0, vr1;
    #define LOADREGS(KT0) \
        kr0 = *(const bf16x8*)&kTb[(size_t)((KT0) + sk0) * CC + sp0 * 8]; \
        kr1 = *(const bf16x8*)&kTb[(size_t)((KT0) + sk1) * CC + sp1 * 8]; \
        vr0 = *(const bf16x8*)&vNb[(size_t)sd0 * LL + (KT0) + sv0 * 8];   \
        vr1 = *(const bf16x8*)&vNb[(size_t)sd1 * LL + (KT0) + sv1 * 8];
    #define WRITEBUF(BUF) \
        *(bf16x8*)&KB[BUF][kw0] = kr0; *(bf16x8*)&KB[BUF][kw1] = kr1; \
        *(bf16x8*)&VB[BUF][vw0] = vr0; *(bf16x8*)&VB[BUF][vw1] = vr1;

    // T4 barrier: drain LDS only; vmcnt loads stay in flight (rule #18 fence)
    #define BARRIER() \
        asm volatile("s_waitcnt lgkmcnt(0)\n\ts_barrier" ::: "memory"); \
        __builtin_amdgcn_sched_barrier(0);

    LOADREGS(0)
    WRITEBUF(0)
    LOADREGS(256)

    f32x16 O0, O1;
    #pragma unroll
    for (int r = 0; r < 16; ++r) { O0[r] = 0.f; O1[r] = 0.f; }
    float ssum = 0.f;
    f32x16 Z16;
    #pragma unroll
    for (int r = 0; r < 16; ++r) Z16[r] = 0.f;

    #define QKC(kbv, S) { \
        const int key_ = (kbv) + lq; \
        const int ksw_ = (key_ >> 1) & 3; \
        const bf16x8 kf0_ = *(const bf16x8*)&KBb[key_ * 32 + ((hi    ) ^ ksw_) * 8]; \
        const bf16x8 kf1_ = *(const bf16x8*)&KBb[key_ * 32 + ((2 + hi) ^ ksw_) * 8]; \
        S = __builtin_amdgcn_mfma_f32_32x32x16_bf16(kf0_, qf0, Z16, 0, 0, 0); \
        S = __builtin_amdgcn_mfma_f32_32x32x16_bf16(kf1_, qf1, S, 0, 0, 0); }

    #define SMC(S, P0, P1) { \
        float e_[16]; \
        _Pragma("unroll") \
        for (int r = 0; r < 16; ++r) e_[r] = __builtin_amdgcn_exp2f(S[r]); \
        float s_ = 0.f; \
        _Pragma("unroll") \
        for (int r = 0; r < 16; r += 4) s_ += (e_[r] + e_[r+1]) + (e_[r+2] + e_[r+3]); \
        ssum += s_; \
        unsigned a_[8]; \
        _Pragma("unroll") \
        for (int i = 0; i < 8; ++i) a_[i] = pkbf(e_[2*i], e_[2*i+1]); \
        { unsigned w0_ = a_[0], w1_ = a_[1], w2_ = a_[2], w3_ = a_[3]; \
          asm volatile("v_permlane32_swap_b32 %0, %1" : "+v"(w0_), "+v"(w2_)); \
          asm volatile("v_permlane32_swap_b32 %0, %1" : "+v"(w1_), "+v"(w3_)); \
          P0 = (u32x4){w0_, w1_, w2_, w3_}; } \
        { unsigned w0_ = a_[4], w1_ = a_[5], w2_ = a_[6], w3_ = a_[7]; \
          asm volatile("v_permlane32_swap_b32 %0, %1" : "+v"(w0_), "+v"(w2_)); \
          asm volatile("v_permlane32_swap_b32 %0, %1" : "+v"(w1_), "+v"(w3_)); \
          P1 = (u32x4){w0_, w1_, w2_, w3_}; } }

    #define PVC(kbv, P0, P1, OA) { \
        const bf16x8 pf0_ = __builtin_bit_cast(bf16x8, P0); \
        const bf16x8 vf0_ = *(const bf16x8*)&VBb[lq * 256 + ((((kbv) >> 3) + hi    ) ^ (lq & 7)) * 8]; \
        OA = __builtin_amdgcn_mfma_f32_32x32x16_bf16(vf0_, pf0_, OA, 0, 0, 0); \
        const bf16x8 pf1_ = __builtin_bit_cast(bf16x8, P1); \
        const bf16x8 vf1_ = *(const bf16x8*)&VBb[lq * 256 + ((((kbv) >> 3) + 2 + hi) ^ (lq & 7)) * 8]; \
        OA = __builtin_amdgcn_mfma_f32_32x32x16_bf16(vf1_, pf1_, OA, 0, 0, 0); }

    const int NT = LL / 256;   // 8
    for (int it = 0; it < NT; ++it) {
        const int buf = it & 1;
        BARRIER()
        if (it + 1 < NT) { WRITEBUF(buf ^ 1) }
        if (it + 2 < NT) { LOADREGS((it + 2) * 256) }

        const __bf16* KBb = KB[buf];
        const __bf16* VBb = VB[buf];

        #pragma unroll
        for (int hf = 0; hf < 2; ++hf) {
            const int kbb = hf * 128;
            f32x16 S0, S1;
            u32x4 Pa, Pb;
            QKC(kbb +  0, S0)
            QKC(kbb + 32, S1)
            SMC(S0, Pa, Pb)
            PVC(kbb +  0, Pa, Pb, O0)
            QKC(kbb + 64, S0)
            SMC(S1, Pa, Pb)
            PVC(kbb + 32, Pa, Pb, O1)
            QKC(kbb + 96, S1)
            SMC(S0, Pa, Pb)
            PVC(kbb + 64, Pa, Pb, O0)
            SMC(S1, Pa, Pb)
            PVC(kbb + 96, Pa, Pb, O1)
        }
    }
    #undef LOADREGS
    #undef WRITEBUF
    #undef BARRIER
    #undef QKC
    #undef SMC
    #undef PVC

    ssum += __shfl_xor(ssum, 32);
    const float inv = 1.f / ssum;

    __bf16* arow = aT + ((size_t)(b * LL) + q0 + lq) * CC + h * DD;
    #pragma unroll
    for (int gi = 0; gi < 4; ++gi) {
        bf16x4 ov;
        #pragma unroll
        for (int r = 0; r < 4; ++r) ov[r] = (__bf16)((O0[4*gi + r] + O1[4*gi + r]) * inv);
        *(bf16x4*)&arow[8 * gi + 4 * hi] = ov;
    }
}

// ---------------------------------------------------------------------------
// outproj (round-6 verified): out fp32 [b][c][l] = wo . a + bo + q.
// tile 64 o x 64 l, grid (32,4,4) block 256 (4 waves, 2Mx2N).
// ---------------------------------------------------------------------------
__global__ __launch_bounds__(256) void outproj_kernel(
    const float* __restrict__ W, const __bf16* __restrict__ X,
    const float* __restrict__ bias, const float* __restrict__ resid,
    float* __restrict__ outF)
{
    __shared__ __align__(16) __bf16 Wl[64][136];
    __shared__ __align__(16) __bf16 Xl[64][136];

    const int lt = blockIdx.x * 64;
    const int ot = blockIdx.y * 64;
    const int b  = blockIdx.z;
    const int t  = threadIdx.x;
    const int wvi = t >> 6;
    const int wm = wvi >> 1;
    const int wn = wvi & 1;
    const int l  = t & 63;
    const int lq = l & 15;
    const int g  = l >> 4;

    f32x4 acc[2][2];
    #pragma unroll
    for (int mi = 0; mi < 2; ++mi)
        #pragma unroll
        for (int ni = 0; ni < 2; ++ni) acc[mi][ni] = (f32x4){0.f,0.f,0.f,0.f};

    for (int ks = 0; ks < 2; ++ks) {
        __syncthreads();
        #pragma unroll
        for (int i = 0; i < 8; ++i) {
            const int idx = i * 256 + t;
            const int row = idx >> 5;
            const int ch  = idx & 31;
            const float4 w4 = *(const float4*)&W[(size_t)(ot + row) * CC + ks * 128 + ch * 4];
            bf16x4 wb;
            wb[0] = (__bf16)w4.x; wb[1] = (__bf16)w4.y;
            wb[2] = (__bf16)w4.z; wb[3] = (__bf16)w4.w;
            *(bf16x4*)&Wl[row][ch * 4] = wb;
        }
        #pragma unroll
        for (int i = 0; i < 4; ++i) {
            const int idx = i * 256 + t;
            const int row = idx >> 4, ch = idx & 15;
            *(bf16x8*)&Xl[row][ch * 8] =
                *(const bf16x8*)&X[(size_t)(b * LL + lt + row) * CC + ks * 128 + ch * 8];
        }
        __syncthreads();

        #pragma unroll
        for (int kk = 0; kk < 4; ++kk) {
            bf16x8 af[2], bfr[2];
            #pragma unroll
            for (int mi = 0; mi < 2; ++mi)
                af[mi] = *(const bf16x8*)&Wl[wm * 32 + mi * 16 + lq][kk * 32 + g * 8];
            #pragma unroll
            for (int ni = 0; ni < 2; ++ni)
                bfr[ni] = *(const bf16x8*)&Xl[wn * 32 + ni * 16 + lq][kk * 32 + g * 8];
            #pragma unroll
            for (int mi = 0; mi < 2; ++mi)
                #pragma unroll
                for (int ni = 0; ni < 2; ++ni)
                    acc[mi][ni] = __builtin_amdgcn_mfma_f32_16x16x32_bf16(
                        af[mi], bfr[ni], acc[mi][ni], 0, 0, 0);
        }
    }

    #pragma unroll
    for (int mi = 0; mi < 2; ++mi) {
        const float4 b4 = *(const float4*)&bias[ot + wm * 32 + mi * 16 + g * 4];
        const float bb[4] = {b4.x, b4.y, b4.z, b4.w};
        #pragma unroll
        for (int ni = 0; ni < 2; ++ni) {
            const int col = lt + wn * 32 + ni * 16 + lq;
            #pragma unroll
            for (int r = 0; r < 4; ++r) {
                const int o = ot + wm * 32 + mi * 16 + g * 4 + r;
                const size_t a = (size_t)(b * CC + o) * LL + col;
                outF[a] = acc[mi][ni][r] + bb[r] + resid[a];
            }
        }
    }
}

// ---------------------------------------------------------------------------
extern "C" void kernel_launch(void* const* d_in, const int* in_sizes, int n_in,
                              void* d_out, int out_size, void* d_ws, size_t ws_size,
                              hipStream_t stream)
{
    const float* v     = (const float*)d_in[0];
    const float* k     = (const float*)d_in[1];
    const float* q     = (const float*)d_in[2];
    const float* pe_q  = (const float*)d_in[3];
    const float* pe_vk = (const float*)d_in[4];
    const float* wq    = (const float*)d_in[5];
    const float* bq    = (const float*)d_in[6];
    const float* gq    = (const float*)d_in[7];
    const float* betaq = (const float*)d_in[8];
    const float* mq    = (const float*)d_in[9];
    const float* varq  = (const float*)d_in[10];
    const float* wk    = (const float*)d_in[11];
    const float* bk    = (const float*)d_in[12];
    const float* gk    = (const float*)d_in[13];
    const float* betak = (const float*)d_in[14];
    const float* mk    = (const float*)d_in[15];
    const float* vark  = (const float*)d_in[16];
    const float* wv    = (const float*)d_in[17];
    const float* bv    = (const float*)d_in[18];
    const float* gv    = (const float*)d_in[19];
    const float* betav = (const float*)d_in[20];
    const float* mv    = (const float*)d_in[21];
    const float* varv  = (const float*)d_in[22];
    const float* wo    = (const float*)d_in[23];
    const float* bo    = (const float*)d_in[24];

    float* out = (float*)d_out;

    const size_t E = (size_t)BB * CC * LL;   // 2,097,152
    __bf16* qT  = (__bf16*)d_ws;
    __bf16* kT  = qT + E;
    __bf16* vN  = kT + E;
    __bf16* aT  = vN + E;

    const float qscale = 0.17677669529663687f * 1.4426950408889634f; // 1/sqrt(32)*log2e

    hipLaunchKernelGGL(qkv_gemm_kernel, dim3(16, 4, 12), dim3(512), 0, stream,
                       q, k, v, pe_q, pe_vk,
                       wq, bq, gq, betaq, mq, varq,
                       wk, bk, gk, betak, mk, vark,
                       wv, bv, gv, betav, mv, varv,
                       qT, kT, vN, qscale);

    hipLaunchKernelGGL(attn_mfma_kernel, dim3(8, HH, BB), dim3(512), 0, stream,
                       qT, kT, vN, aT);

    hipLaunchKernelGGL(outproj_kernel, dim3(32, 4, 4), dim3(256), 0, stream,
                       wo, aT, bo, q, out);
}

// Round 17
// 58.157 us; speedup vs baseline: 1.0164x; 1.0164x over previous
//
#include <hip/hip_runtime.h>
#include <hip/hip_bf16.h>

#define BB 4
#define CC 256   // CQ == CVK == 256
#define LL 2048
#define HH 8
#define DD 32
#define EPSV 1e-5f

typedef __bf16 bf16x8 __attribute__((ext_vector_type(8)));
typedef __bf16 bf16x4 __attribute__((ext_vector_type(4)));
typedef __bf16 bf16x2 __attribute__((ext_vector_type(2)));
typedef float  f32x4  __attribute__((ext_vector_type(4)));
typedef float  f32x16 __attribute__((ext_vector_type(16)));
typedef unsigned int u32x4 __attribute__((ext_vector_type(4)));

static __device__ __forceinline__ unsigned pkbf(float lo, float hi) {
    bf16x2 p; p[0] = (__bf16)lo; p[1] = (__bf16)hi;
    return __builtin_bit_cast(unsigned, p);
}

// ---------------------------------------------------------------------------
// qkv gemm (round-6 verified): fp32 x + pe staged with in-LDS transpose+cast,
// fp32 weights BN-folded+cast during staging.  grid (16,4,12): z=which*4+b.
// block 512 (8 waves, 2Mx4N), tile 64 o x 128 l, K=256 (2 steps of 128).
// which<2 -> T-layout bf16 out via LDS transpose; which==2 -> natural bf16.
// ---------------------------------------------------------------------------
__global__ __launch_bounds__(512) void qkv_gemm_kernel(
    const float* __restrict__ qin, const float* __restrict__ kin,
    const float* __restrict__ vin,
    const float* __restrict__ peq, const float* __restrict__ pevk,
    const float* __restrict__ wq, const float* __restrict__ bq,
    const float* __restrict__ gq, const float* __restrict__ betaq,
    const float* __restrict__ mq, const float* __restrict__ varq,
    const float* __restrict__ wk, const float* __restrict__ bk,
    const float* __restrict__ gk, const float* __restrict__ betak,
    const float* __restrict__ mk, const float* __restrict__ vark,
    const float* __restrict__ wv, const float* __restrict__ bv,
    const float* __restrict__ gv, const float* __restrict__ betav,
    const float* __restrict__ mv, const float* __restrict__ varv,
    __bf16* __restrict__ qTo, __bf16* __restrict__ kTo, __bf16* __restrict__ vNo,
    float qscale)
{
    __shared__ __align__(16) __bf16 Wl[64][136];
    __shared__ __align__(16) __bf16 Xl[128][136];
    __bf16 (*Tl)[72] = (__bf16(*)[72])Xl;

    const int z = blockIdx.z;
    const int which = z >> 2;
    const int b = z & 3;
    const float* X    = which==0 ? qin : (which==1 ? kin : vin);
    const float* pe   = which==0 ? peq : pevk;
    const float* W    = which==0 ? wq  : (which==1 ? wk  : wv);
    const float* bia  = which==0 ? bq  : (which==1 ? bk  : bv);
    const float* gam  = which==0 ? gq  : (which==1 ? gk  : gv);
    const float* bet  = which==0 ? betaq : (which==1 ? betak : betav);
    const float* mea  = which==0 ? mq  : (which==1 ? mk  : mv);
    const float* var  = which==0 ? varq : (which==1 ? vark : varv);
    const float extra = (which==0) ? qscale : 1.0f;

    const int lt = blockIdx.x * 128;
    const int ot = blockIdx.y * 64;
    const int t  = threadIdx.x;
    const int wvi = t >> 6;
    const int wm = wvi >> 2;
    const int wn = wvi & 3;
    const int l  = t & 63;
    const int lq = l & 15;
    const int g  = l >> 4;

    f32x4 acc[2][2];
    #pragma unroll
    for (int mi = 0; mi < 2; ++mi)
        #pragma unroll
        for (int ni = 0; ni < 2; ++ni) acc[mi][ni] = (f32x4){0.f,0.f,0.f,0.f};

    for (int ks = 0; ks < 2; ++ks) {
        __syncthreads();
        #pragma unroll
        for (int i = 0; i < 4; ++i) {
            const int idx = i * 512 + t;
            const int row = idx >> 5;
            const int ch  = idx & 31;
            const int o   = ot + row;
            const float sc = gam[o] * rsqrtf(var[o] + EPSV) * extra;
            const float4 w4 = *(const float4*)&W[(size_t)o * CC + ks * 128 + ch * 4];
            bf16x4 wb;
            wb[0] = (__bf16)(w4.x * sc); wb[1] = (__bf16)(w4.y * sc);
            wb[2] = (__bf16)(w4.z * sc); wb[3] = (__bf16)(w4.w * sc);
            *(bf16x4*)&Wl[row][ch * 4] = wb;
        }
        #pragma unroll
        for (int i = 0; i < 2; ++i) {
            const int slot = i * 512 + t;
            const int lp = slot & 63;
            const int co = slot >> 6;
            const float* xp = &X[(size_t)(b * CC + ks * 128 + co * 8) * LL + lt + lp * 2];
            const float* pp = &pe[(size_t)(ks * 128 + co * 8) * LL + lt + lp * 2];
            bf16x8 lo, hi;
            #pragma unroll
            for (int j = 0; j < 8; ++j) {
                const float2 a = *(const float2*)&xp[(size_t)j * LL];
                const float2 p = *(const float2*)&pp[(size_t)j * LL];
                lo[j] = (__bf16)(a.x + p.x);
                hi[j] = (__bf16)(a.y + p.y);
            }
            *(bf16x8*)&Xl[lp * 2    ][co * 8] = lo;
            *(bf16x8*)&Xl[lp * 2 + 1][co * 8] = hi;
        }
        __syncthreads();

        #pragma unroll
        for (int kk = 0; kk < 4; ++kk) {
            bf16x8 af[2], bfr[2];
            #pragma unroll
            for (int mi = 0; mi < 2; ++mi)
                af[mi] = *(const bf16x8*)&Wl[wm * 32 + mi * 16 + lq][kk * 32 + g * 8];
            #pragma unroll
            for (int ni = 0; ni < 2; ++ni)
                bfr[ni] = *(const bf16x8*)&Xl[wn * 32 + ni * 16 + lq][kk * 32 + g * 8];
            #pragma unroll
            for (int mi = 0; mi < 2; ++mi)
                #pragma unroll
                for (int ni = 0; ni < 2; ++ni)
                    acc[mi][ni] = __builtin_amdgcn_mfma_f32_16x16x32_bf16(
                        af[mi], bfr[ni], acc[mi][ni], 0, 0, 0);
        }
    }

    float bb[2][4];
    #pragma unroll
    for (int mi = 0; mi < 2; ++mi) {
        const int o4 = ot + wm * 32 + mi * 16 + g * 4;
        const float4 b4 = *(const float4*)&bia[o4];
        const float4 g4 = *(const float4*)&gam[o4];
        const float4 v4 = *(const float4*)&var[o4];
        const float4 m4 = *(const float4*)&mea[o4];
        const float4 t4 = *(const float4*)&bet[o4];
        const float bs[4] = {b4.x,b4.y,b4.z,b4.w};
        const float gs[4] = {g4.x,g4.y,g4.z,g4.w};
        const float vs[4] = {v4.x,v4.y,v4.z,v4.w};
        const float ms[4] = {m4.x,m4.y,m4.z,m4.w};
        const float ts[4] = {t4.x,t4.y,t4.z,t4.w};
        #pragma unroll
        for (int r = 0; r < 4; ++r) {
            const float sc = gs[r] * rsqrtf(vs[r] + EPSV);
            bb[mi][r] = ((bs[r] - ms[r]) * sc + ts[r]) * extra;
        }
    }

    if (which < 2) {
        __bf16* outT = which==0 ? qTo : kTo;
        __syncthreads();
        #pragma unroll
        for (int mi = 0; mi < 2; ++mi) {
            #pragma unroll
            for (int ni = 0; ni < 2; ++ni) {
                bf16x4 pv;
                #pragma unroll
                for (int r = 0; r < 4; ++r) pv[r] = (__bf16)(acc[mi][ni][r] + bb[mi][r]);
                *(bf16x4*)&Tl[wn * 32 + ni * 16 + lq][wm * 32 + mi * 16 + g * 4] = pv;
            }
        }
        __syncthreads();
        #pragma unroll
        for (int i = 0; i < 2; ++i) {
            const int idx = i * 512 + t;
            const int lrow = idx >> 3, ch = idx & 7;
            *(bf16x8*)&outT[(size_t)(b * LL + lt + lrow) * CC + ot + ch * 8] =
                *(const bf16x8*)&Tl[lrow][ch * 8];
        }
    } else {
        #pragma unroll
        for (int mi = 0; mi < 2; ++mi) {
            #pragma unroll
            for (int ni = 0; ni < 2; ++ni) {
                const int col = lt + wn * 32 + ni * 16 + lq;
                #pragma unroll
                for (int r = 0; r < 4; ++r) {
                    const int o = ot + wm * 32 + mi * 16 + g * 4 + r;
                    vNo[(size_t)(b * CC + o) * LL + col] = (__bf16)(acc[mi][ni][r] + bb[mi][r]);
                }
            }
        }
    }
}

// ---------------------------------------------------------------------------
// attn (round-15 verified BEST): 8 waves x 32 queries (256 q/block) over all
// 2048 keys; K/V tile (128 keys) staged once per 256 queries by 512 threads.
// 32x32 MFMA, in-register softmax (permlane32_swap), XOR-swizzled
// double-buffered K/V, depth-2 pipelined chunks, O0/O1 split, T4 lgkm-only
// barrier, XCD remap.  grid (8,8,4) = 256 blocks, LDS 32KB -> 2 blocks/CU.
// ---------------------------------------------------------------------------
__global__ __launch_bounds__(512, 2) void attn_mfma_kernel(
    const __bf16* __restrict__ qT, const __bf16* __restrict__ kT,
    const __bf16* __restrict__ vN, __bf16* __restrict__ aT)
{
    __shared__ __align__(16) __bf16 KB[2][128 * 32];   // [key][d], slot-swizzled
    __shared__ __align__(16) __bf16 VB[2][32 * 128];   // [d][key], slot-swizzled

    // XCD remap: 256 blocks, 32 (b,h) groups (4/XCD), 8 q-blocks per group.
    const int flat = blockIdx.x + 8 * (blockIdx.y + 8 * blockIdx.z);
    const int xcd  = flat & 7;
    const int ixc  = flat >> 3;              // 0..31
    const int gidx = xcd + 8 * (ixc >> 3);   // 0..31 : (b,h) group
    const int qb   = ixc & 7;
    const int h    = gidx & 7;
    const int b    = gidx >> 3;

    const int t  = threadIdx.x;   // 0..511
    const int w  = t >> 6;        // 0..7
    const int l  = t & 63;
    const int lq = l & 31;
    const int hi = l >> 5;

    const int q0 = qb * 256 + w * 32;

    const __bf16* qrow = qT + ((size_t)(b * LL) + q0 + lq) * CC + h * DD;
    const bf16x8 qf0 = *(const bf16x8*)&qrow[hi * 8];
    const bf16x8 qf1 = *(const bf16x8*)&qrow[16 + hi * 8];

    const __bf16* kTb = kT + (size_t)(b * LL) * CC + h * DD;
    const __bf16* vNb = vN + ((size_t)(b * CC) + h * DD) * LL;

    // staging: 512 threads, one K slot + one V slot each.
    const int sk = t >> 2, sp = t & 3;      // K: 128 keys x 4 chunks
    const int sd = t >> 4, sv = t & 15;     // V: 32 d x 16 chunks
    const int kw = sk * 32 + (sp ^ ((sk >> 1) & 3)) * 8;
    const int vw = sd * 128 + (sv ^ (sd & 7)) * 8;

    bf16x8 kr, vr;
    #define LOADREGS(KT0) \
        kr = *(const bf16x8*)&kTb[(size_t)((KT0) + sk) * CC + sp * 8]; \
        vr = *(const bf16x8*)&vNb[(size_t)sd * LL + (KT0) + sv * 8];
    #define WRITEBUF(BUF) \
        *(bf16x8*)&KB[BUF][kw] = kr; *(bf16x8*)&VB[BUF][vw] = vr;

    // T4 barrier: drain LDS only; vmcnt loads stay in flight (rule #18 fence)
    #define BARRIER() \
        asm volatile("s_waitcnt lgkmcnt(0)\n\ts_barrier" ::: "memory"); \
        __builtin_amdgcn_sched_barrier(0);

    LOADREGS(0)
    WRITEBUF(0)
    LOADREGS(128)

    f32x16 O0, O1;
    #pragma unroll
    for (int r = 0; r < 16; ++r) { O0[r] = 0.f; O1[r] = 0.f; }
    float ssum = 0.f;
    f32x16 Z16;
    #pragma unroll
    for (int r = 0; r < 16; ++r) Z16[r] = 0.f;

    #define QKC(kbv, S) { \
        const int key_ = (kbv) + lq; \
        const int ksw_ = (key_ >> 1) & 3; \
        const bf16x8 kf0_ = *(const bf16x8*)&KBb[key_ * 32 + ((hi    ) ^ ksw_) * 8]; \
        const bf16x8 kf1_ = *(const bf16x8*)&KBb[key_ * 32 + ((2 + hi) ^ ksw_) * 8]; \
        S = __builtin_amdgcn_mfma_f32_32x32x16_bf16(kf0_, qf0, Z16, 0, 0, 0); \
        S = __builtin_amdgcn_mfma_f32_32x32x16_bf16(kf1_, qf1, S, 0, 0, 0); }

    #define SMC(S, P0, P1) { \
        float e_[16]; \
        _Pragma("unroll") \
        for (int r = 0; r < 16; ++r) e_[r] = __builtin_amdgcn_exp2f(S[r]); \
        float s_ = 0.f; \
        _Pragma("unroll") \
        for (int r = 0; r < 16; r += 4) s_ += (e_[r] + e_[r+1]) + (e_[r+2] + e_[r+3]); \
        ssum += s_; \
        unsigned a_[8]; \
        _Pragma("unroll") \
        for (int i = 0; i < 8; ++i) a_[i] = pkbf(e_[2*i], e_[2*i+1]); \
        { unsigned w0_ = a_[0], w1_ = a_[1], w2_ = a_[2], w3_ = a_[3]; \
          asm volatile("v_permlane32_swap_b32 %0, %1" : "+v"(w0_), "+v"(w2_)); \
          asm volatile("v_permlane32_swap_b32 %0, %1" : "+v"(w1_), "+v"(w3_)); \
          P0 = (u32x4){w0_, w1_, w2_, w3_}; } \
        { unsigned w0_ = a_[4], w1_ = a_[5], w2_ = a_[6], w3_ = a_[7]; \
          asm volatile("v_permlane32_swap_b32 %0, %1" : "+v"(w0_), "+v"(w2_)); \
          asm volatile("v_permlane32_swap_b32 %0, %1" : "+v"(w1_), "+v"(w3_)); \
          P1 = (u32x4){w0_, w1_, w2_, w3_}; } }

    #define PVC(kbv, P0, P1, OA) { \
        const bf16x8 pf0_ = __builtin_bit_cast(bf16x8, P0); \
        const bf16x8 vf0_ = *(const bf16x8*)&VBb[lq * 128 + ((((kbv) >> 3) + hi    ) ^ (lq & 7)) * 8]; \
        OA = __builtin_amdgcn_mfma_f32_32x32x16_bf16(vf0_, pf0_, OA, 0, 0, 0); \
        const bf16x8 pf1_ = __builtin_bit_cast(bf16x8, P1); \
        const bf16x8 vf1_ = *(const bf16x8*)&VBb[lq * 128 + ((((kbv) >> 3) + 2 + hi) ^ (lq & 7)) * 8]; \
        OA = __builtin_amdgcn_mfma_f32_32x32x16_bf16(vf1_, pf1_, OA, 0, 0, 0); }

    const int NT = LL / 128;   // 16
    for (int it = 0; it < NT; ++it) {
        const int buf = it & 1;
        BARRIER()
        if (it + 1 < NT) { WRITEBUF(buf ^ 1) }
        if (it + 2 < NT) { LOADREGS((it + 2) * 128) }

        const __bf16* KBb = KB[buf];
        const __bf16* VBb = VB[buf];

        f32x16 S0, S1;
        u32x4 Pa, Pb;
        QKC(0,  S0)
        QKC(32, S1)
        SMC(S0, Pa, Pb)
        PVC(0,  Pa, Pb, O0)
        QKC(64, S0)
        SMC(S1, Pa, Pb)
        PVC(32, Pa, Pb, O1)
        QKC(96, S1)
        SMC(S0, Pa, Pb)
        PVC(64, Pa, Pb, O0)
        SMC(S1, Pa, Pb)
        PVC(96, Pa, Pb, O1)
    }
    #undef LOADREGS
    #undef WRITEBUF
    #undef BARRIER
    #undef QKC
    #undef SMC
    #undef PVC

    ssum += __shfl_xor(ssum, 32);
    const float inv = 1.f / ssum;

    __bf16* arow = aT + ((size_t)(b * LL) + q0 + lq) * CC + h * DD;
    #pragma unroll
    for (int gi = 0; gi < 4; ++gi) {
        bf16x4 ov;
        #pragma unroll
        for (int r = 0; r < 4; ++r) ov[r] = (__bf16)((O0[4*gi + r] + O1[4*gi + r]) * inv);
        *(bf16x4*)&arow[8 * gi + 4 * hi] = ov;
    }
}

// ---------------------------------------------------------------------------
// outproj (round-6 verified): out fp32 [b][c][l] = wo . a + bo + q.
// tile 64 o x 64 l, grid (32,4,4) block 256 (4 waves, 2Mx2N).
// ---------------------------------------------------------------------------
__global__ __launch_bounds__(256) void outproj_kernel(
    const float* __restrict__ W, const __bf16* __restrict__ X,
    const float* __restrict__ bias, const float* __restrict__ resid,
    float* __restrict__ outF)
{
    __shared__ __align__(16) __bf16 Wl[64][136];
    __shared__ __align__(16) __bf16 Xl[64][136];

    const int lt = blockIdx.x * 64;
    const int ot = blockIdx.y * 64;
    const int b  = blockIdx.z;
    const int t  = threadIdx.x;
    const int wvi = t >> 6;
    const int wm = wvi >> 1;
    const int wn = wvi & 1;
    const int l  = t & 63;
    const int lq = l & 15;
    const int g  = l >> 4;

    f32x4 acc[2][2];
    #pragma unroll
    for (int mi = 0; mi < 2; ++mi)
        #pragma unroll
        for (int ni = 0; ni < 2; ++ni) acc[mi][ni] = (f32x4){0.f,0.f,0.f,0.f};

    for (int ks = 0; ks < 2; ++ks) {
        __syncthreads();
        #pragma unroll
        for (int i = 0; i < 8; ++i) {
            const int idx = i * 256 + t;
            const int row = idx >> 5;
            const int ch  = idx & 31;
            const float4 w4 = *(const float4*)&W[(size_t)(ot + row) * CC + ks * 128 + ch * 4];
            bf16x4 wb;
            wb[0] = (__bf16)w4.x; wb[1] = (__bf16)w4.y;
            wb[2] = (__bf16)w4.z; wb[3] = (__bf16)w4.w;
            *(bf16x4*)&Wl[row][ch * 4] = wb;
        }
        #pragma unroll
        for (int i = 0; i < 4; ++i) {
            const int idx = i * 256 + t;
            const int row = idx >> 4, ch = idx & 15;
            *(bf16x8*)&Xl[row][ch * 8] =
                *(const bf16x8*)&X[(size_t)(b * LL + lt + row) * CC + ks * 128 + ch * 8];
        }
        __syncthreads();

        #pragma unroll
        for (int kk = 0; kk < 4; ++kk) {
            bf16x8 af[2], bfr[2];
            #pragma unroll
            for (int mi = 0; mi < 2; ++mi)
                af[mi] = *(const bf16x8*)&Wl[wm * 32 + mi * 16 + lq][kk * 32 + g * 8];
            #pragma unroll
            for (int ni = 0; ni < 2; ++ni)
                bfr[ni] = *(const bf16x8*)&Xl[wn * 32 + ni * 16 + lq][kk * 32 + g * 8];
            #pragma unroll
            for (int mi = 0; mi < 2; ++mi)
                #pragma unroll
                for (int ni = 0; ni < 2; ++ni)
                    acc[mi][ni] = __builtin_amdgcn_mfma_f32_16x16x32_bf16(
                        af[mi], bfr[ni], acc[mi][ni], 0, 0, 0);
        }
    }

    #pragma unroll
    for (int mi = 0; mi < 2; ++mi) {
        const float4 b4 = *(const float4*)&bias[ot + wm * 32 + mi * 16 + g * 4];
        const float bb[4] = {b4.x, b4.y, b4.z, b4.w};
        #pragma unroll
        for (int ni = 0; ni < 2; ++ni) {
            const int col = lt + wn * 32 + ni * 16 + lq;
            #pragma unroll
            for (int r = 0; r < 4; ++r) {
                const int o = ot + wm * 32 + mi * 16 + g * 4 + r;
                const size_t a = (size_t)(b * CC + o) * LL + col;
                outF[a] = acc[mi][ni][r] + bb[r] + resid[a];
            }
        }
    }
}

// ---------------------------------------------------------------------------
extern "C" void kernel_launch(void* const* d_in, const int* in_sizes, int n_in,
                              void* d_out, int out_size, void* d_ws, size_t ws_size,
                              hipStream_t stream)
{
    const float* v     = (const float*)d_in[0];
    const float* k     = (const float*)d_in[1];
    const float* q     = (const float*)d_in[2];
    const float* pe_q  = (const float*)d_in[3];
    const float* pe_vk = (const float*)d_in[4];
    const float* wq    = (const float*)d_in[5];
    const float* bq    = (const float*)d_in[6];
    const float* gq    = (const float*)d_in[7];
    const float* betaq = (const float*)d_in[8];
    const float* mq    = (const float*)d_in[9];
    const float* varq  = (const float*)d_in[10];
    const float* wk    = (const float*)d_in[11];
    const float* bk    = (const float*)d_in[12];
    const float* gk    = (const float*)d_in[13];
    const float* betak = (const float*)d_in[14];
    const float* mk    = (const float*)d_in[15];
    const float* vark  = (const float*)d_in[16];
    const float* wv    = (const float*)d_in[17];
    const float* bv    = (const float*)d_in[18];
    const float* gv    = (const float*)d_in[19];
    const float* betav = (const float*)d_in[20];
    const float* mv    = (const float*)d_in[21];
    const float* varv  = (const float*)d_in[22];
    const float* wo    = (const float*)d_in[23];
    const float* bo    = (const float*)d_in[24];

    float* out = (float*)d_out;

    const size_t E = (size_t)BB * CC * LL;   // 2,097,152
    __bf16* qT  = (__bf16*)d_ws;
    __bf16* kT  = qT + E;
    __bf16* vN  = kT + E;
    __bf16* aT  = vN + E;

    const float qscale = 0.17677669529663687f * 1.4426950408889634f; // 1/sqrt(32)*log2e

    hipLaunchKernelGGL(qkv_gemm_kernel, dim3(16, 4, 12), dim3(512), 0, stream,
                       q, k, v, pe_q, pe_vk,
                       wq, bq, gq, betaq, mq, varq,
                       wk, bk, gk, betak, mk, vark,
                       wv, bv, gv, betav, mv, varv,
                       qT, kT, vN, qscale);

    hipLaunchKernelGGL(attn_mfma_kernel, dim3(8, HH, BB), dim3(512), 0, stream,
                       qT, kT, vN, aT);

    hipLaunchKernelGGL(outproj_kernel, dim3(32, 4, 4), dim3(256), 0, stream,
                       wo, aT, bo, q, out);
}

// Round 18
// 58.015 us; speedup vs baseline: 1.0189x; 1.0024x over previous
//
#include <hip/hip_runtime.h>
#include <hip/hip_bf16.h>

#define BB 4
#define CC 256   // CQ == CVK == 256
#define LL 2048
#define HH 8
#define DD 32
#define EPSV 1e-5f

typedef __bf16 bf16x8 __attribute__((ext_vector_type(8)));
typedef __bf16 bf16x4 __attribute__((ext_vector_type(4)));
typedef __bf16 bf16x2 __attribute__((ext_vector_type(2)));
typedef float  f32x4  __attribute__((ext_vector_type(4)));
typedef float  f32x16 __attribute__((ext_vector_type(16)));
typedef unsigned int u32x4 __attribute__((ext_vector_type(4)));

static __device__ __forceinline__ unsigned pkbf(float lo, float hi) {
    bf16x2 p; p[0] = (__bf16)lo; p[1] = (__bf16)hi;
    return __builtin_bit_cast(unsigned, p);
}

// ---------------------------------------------------------------------------
// qkv gemm (round-6 verified): fp32 x + pe staged with in-LDS transpose+cast,
// fp32 weights BN-folded+cast during staging.  grid (16,4,12): z=which*4+b.
// block 512 (8 waves, 2Mx4N), tile 64 o x 128 l, K=256 (2 steps of 128).
// which<2 -> T-layout bf16 out via LDS transpose; which==2 -> natural bf16.
// ---------------------------------------------------------------------------
__global__ __launch_bounds__(512) void qkv_gemm_kernel(
    const float* __restrict__ qin, const float* __restrict__ kin,
    const float* __restrict__ vin,
    const float* __restrict__ peq, const float* __restrict__ pevk,
    const float* __restrict__ wq, const float* __restrict__ bq,
    const float* __restrict__ gq, const float* __restrict__ betaq,
    const float* __restrict__ mq, const float* __restrict__ varq,
    const float* __restrict__ wk, const float* __restrict__ bk,
    const float* __restrict__ gk, const float* __restrict__ betak,
    const float* __restrict__ mk, const float* __restrict__ vark,
    const float* __restrict__ wv, const float* __restrict__ bv,
    const float* __restrict__ gv, const float* __restrict__ betav,
    const float* __restrict__ mv, const float* __restrict__ varv,
    __bf16* __restrict__ qTo, __bf16* __restrict__ kTo, __bf16* __restrict__ vNo,
    float qscale)
{
    __shared__ __align__(16) __bf16 Wl[64][136];
    __shared__ __align__(16) __bf16 Xl[128][136];
    __bf16 (*Tl)[72] = (__bf16(*)[72])Xl;

    const int z = blockIdx.z;
    const int which = z >> 2;
    const int b = z & 3;
    const float* X    = which==0 ? qin : (which==1 ? kin : vin);
    const float* pe   = which==0 ? peq : pevk;
    const float* W    = which==0 ? wq  : (which==1 ? wk  : wv);
    const float* bia  = which==0 ? bq  : (which==1 ? bk  : bv);
    const float* gam  = which==0 ? gq  : (which==1 ? gk  : gv);
    const float* bet  = which==0 ? betaq : (which==1 ? betak : betav);
    const float* mea  = which==0 ? mq  : (which==1 ? mk  : mv);
    const float* var  = which==0 ? varq : (which==1 ? vark : varv);
    const float extra = (which==0) ? qscale : 1.0f;

    const int lt = blockIdx.x * 128;
    const int ot = blockIdx.y * 64;
    const int t  = threadIdx.x;
    const int wvi = t >> 6;
    const int wm = wvi >> 2;
    const int wn = wvi & 3;
    const int l  = t & 63;
    const int lq = l & 15;
    const int g  = l >> 4;

    f32x4 acc[2][2];
    #pragma unroll
    for (int mi = 0; mi < 2; ++mi)
        #pragma unroll
        for (int ni = 0; ni < 2; ++ni) acc[mi][ni] = (f32x4){0.f,0.f,0.f,0.f};

    for (int ks = 0; ks < 2; ++ks) {
        __syncthreads();
        #pragma unroll
        for (int i = 0; i < 4; ++i) {
            const int idx = i * 512 + t;
            const int row = idx >> 5;
            const int ch  = idx & 31;
            const int o   = ot + row;
            const float sc = gam[o] * rsqrtf(var[o] + EPSV) * extra;
            const float4 w4 = *(const float4*)&W[(size_t)o * CC + ks * 128 + ch * 4];
            bf16x4 wb;
            wb[0] = (__bf16)(w4.x * sc); wb[1] = (__bf16)(w4.y * sc);
            wb[2] = (__bf16)(w4.z * sc); wb[3] = (__bf16)(w4.w * sc);
            *(bf16x4*)&Wl[row][ch * 4] = wb;
        }
        #pragma unroll
        for (int i = 0; i < 2; ++i) {
            const int slot = i * 512 + t;
            const int lp = slot & 63;
            const int co = slot >> 6;
            const float* xp = &X[(size_t)(b * CC + ks * 128 + co * 8) * LL + lt + lp * 2];
            const float* pp = &pe[(size_t)(ks * 128 + co * 8) * LL + lt + lp * 2];
            bf16x8 lo, hi;
            #pragma unroll
            for (int j = 0; j < 8; ++j) {
                const float2 a = *(const float2*)&xp[(size_t)j * LL];
                const float2 p = *(const float2*)&pp[(size_t)j * LL];
                lo[j] = (__bf16)(a.x + p.x);
                hi[j] = (__bf16)(a.y + p.y);
            }
            *(bf16x8*)&Xl[lp * 2    ][co * 8] = lo;
            *(bf16x8*)&Xl[lp * 2 + 1][co * 8] = hi;
        }
        __syncthreads();

        #pragma unroll
        for (int kk = 0; kk < 4; ++kk) {
            bf16x8 af[2], bfr[2];
            #pragma unroll
            for (int mi = 0; mi < 2; ++mi)
                af[mi] = *(const bf16x8*)&Wl[wm * 32 + mi * 16 + lq][kk * 32 + g * 8];
            #pragma unroll
            for (int ni = 0; ni < 2; ++ni)
                bfr[ni] = *(const bf16x8*)&Xl[wn * 32 + ni * 16 + lq][kk * 32 + g * 8];
            #pragma unroll
            for (int mi = 0; mi < 2; ++mi)
                #pragma unroll
                for (int ni = 0; ni < 2; ++ni)
                    acc[mi][ni] = __builtin_amdgcn_mfma_f32_16x16x32_bf16(
                        af[mi], bfr[ni], acc[mi][ni], 0, 0, 0);
        }
    }

    float bb[2][4];
    #pragma unroll
    for (int mi = 0; mi < 2; ++mi) {
        const int o4 = ot + wm * 32 + mi * 16 + g * 4;
        const float4 b4 = *(const float4*)&bia[o4];
        const float4 g4 = *(const float4*)&gam[o4];
        const float4 v4 = *(const float4*)&var[o4];
        const float4 m4 = *(const float4*)&mea[o4];
        const float4 t4 = *(const float4*)&bet[o4];
        const float bs[4] = {b4.x,b4.y,b4.z,b4.w};
        const float gs[4] = {g4.x,g4.y,g4.z,g4.w};
        const float vs[4] = {v4.x,v4.y,v4.z,v4.w};
        const float ms[4] = {m4.x,m4.y,m4.z,m4.w};
        const float ts[4] = {t4.x,t4.y,t4.z,t4.w};
        #pragma unroll
        for (int r = 0; r < 4; ++r) {
            const float sc = gs[r] * rsqrtf(vs[r] + EPSV);
            bb[mi][r] = ((bs[r] - ms[r]) * sc + ts[r]) * extra;
        }
    }

    if (which < 2) {
        __bf16* outT = which==0 ? qTo : kTo;
        __syncthreads();
        #pragma unroll
        for (int mi = 0; mi < 2; ++mi) {
            #pragma unroll
            for (int ni = 0; ni < 2; ++ni) {
                bf16x4 pv;
                #pragma unroll
                for (int r = 0; r < 4; ++r) pv[r] = (__bf16)(acc[mi][ni][r] + bb[mi][r]);
                *(bf16x4*)&Tl[wn * 32 + ni * 16 + lq][wm * 32 + mi * 16 + g * 4] = pv;
            }
        }
        __syncthreads();
        #pragma unroll
        for (int i = 0; i < 2; ++i) {
            const int idx = i * 512 + t;
            const int lrow = idx >> 3, ch = idx & 7;
            *(bf16x8*)&outT[(size_t)(b * LL + lt + lrow) * CC + ot + ch * 8] =
                *(const bf16x8*)&Tl[lrow][ch * 8];
        }
    } else {
        #pragma unroll
        for (int mi = 0; mi < 2; ++mi) {
            #pragma unroll
            for (int ni = 0; ni < 2; ++ni) {
                const int col = lt + wn * 32 + ni * 16 + lq;
                #pragma unroll
                for (int r = 0; r < 4; ++r) {
                    const int o = ot + wm * 32 + mi * 16 + g * 4 + r;
                    vNo[(size_t)(b * CC + o) * LL + col] = (__bf16)(acc[mi][ni][r] + bb[mi][r]);
                }
            }
        }
    }
}

// ---------------------------------------------------------------------------
// attn (round-15 verified best + T5 setprio on MFMA pairs): 8 waves x 32
// queries (256 q/block) over all 2048 keys; K/V tile 128 staged once per 256
// queries.  32x32 MFMA, in-register softmax (permlane32_swap), XOR-swizzled
// double-buffered K/V, depth-2 pipelined chunks, O0/O1 split, T4 lgkm-only
// barrier, XCD remap.  grid (8,8,4) = 256 blocks, LDS 32KB -> 2 blocks/CU
// (independent blocks per CU = wave role-diversity -> setprio applicable).
// ---------------------------------------------------------------------------
__global__ __launch_bounds__(512, 2) void attn_mfma_kernel(
    const __bf16* __restrict__ qT, const __bf16* __restrict__ kT,
    const __bf16* __restrict__ vN, __bf16* __restrict__ aT)
{
    __shared__ __align__(16) __bf16 KB[2][128 * 32];   // [key][d], slot-swizzled
    __shared__ __align__(16) __bf16 VB[2][32 * 128];   // [d][key], slot-swizzled

    // XCD remap: 256 blocks, 32 (b,h) groups (4/XCD), 8 q-blocks per group.
    const int flat = blockIdx.x + 8 * (blockIdx.y + 8 * blockIdx.z);
    const int xcd  = flat & 7;
    const int ixc  = flat >> 3;              // 0..31
    const int gidx = xcd + 8 * (ixc >> 3);   // 0..31 : (b,h) group
    const int qb   = ixc & 7;
    const int h    = gidx & 7;
    const int b    = gidx >> 3;

    const int t  = threadIdx.x;   // 0..511
    const int w  = t >> 6;        // 0..7
    const int l  = t & 63;
    const int lq = l & 31;
    const int hi = l >> 5;

    const int q0 = qb * 256 + w * 32;

    const __bf16* qrow = qT + ((size_t)(b * LL) + q0 + lq) * CC + h * DD;
    const bf16x8 qf0 = *(const bf16x8*)&qrow[hi * 8];
    const bf16x8 qf1 = *(const bf16x8*)&qrow[16 + hi * 8];

    const __bf16* kTb = kT + (size_t)(b * LL) * CC + h * DD;
    const __bf16* vNb = vN + ((size_t)(b * CC) + h * DD) * LL;

    // staging: 512 threads, one K slot + one V slot each.
    const int sk = t >> 2, sp = t & 3;      // K: 128 keys x 4 chunks
    const int sd = t >> 4, sv = t & 15;     // V: 32 d x 16 chunks
    const int kw = sk * 32 + (sp ^ ((sk >> 1) & 3)) * 8;
    const int vw = sd * 128 + (sv ^ (sd & 7)) * 8;

    bf16x8 kr, vr;
    #define LOADREGS(KT0) \
        kr = *(const bf16x8*)&kTb[(size_t)((KT0) + sk) * CC + sp * 8]; \
        vr = *(const bf16x8*)&vNb[(size_t)sd * LL + (KT0) + sv * 8];
    #define WRITEBUF(BUF) \
        *(bf16x8*)&KB[BUF][kw] = kr; *(bf16x8*)&VB[BUF][vw] = vr;

    // T4 barrier: drain LDS only; vmcnt loads stay in flight (rule #18 fence)
    #define BARRIER() \
        asm volatile("s_waitcnt lgkmcnt(0)\n\ts_barrier" ::: "memory"); \
        __builtin_amdgcn_sched_barrier(0);

    LOADREGS(0)
    WRITEBUF(0)
    LOADREGS(128)

    f32x16 O0, O1;
    #pragma unroll
    for (int r = 0; r < 16; ++r) { O0[r] = 0.f; O1[r] = 0.f; }
    float ssum = 0.f;
    f32x16 Z16;
    #pragma unroll
    for (int r = 0; r < 16; ++r) Z16[r] = 0.f;

    #define QKC(kbv, S) { \
        const int key_ = (kbv) + lq; \
        const int ksw_ = (key_ >> 1) & 3; \
        const bf16x8 kf0_ = *(const bf16x8*)&KBb[key_ * 32 + ((hi    ) ^ ksw_) * 8]; \
        const bf16x8 kf1_ = *(const bf16x8*)&KBb[key_ * 32 + ((2 + hi) ^ ksw_) * 8]; \
        __builtin_amdgcn_s_setprio(1); \
        S = __builtin_amdgcn_mfma_f32_32x32x16_bf16(kf0_, qf0, Z16, 0, 0, 0); \
        S = __builtin_amdgcn_mfma_f32_32x32x16_bf16(kf1_, qf1, S, 0, 0, 0); \
        __builtin_amdgcn_s_setprio(0); }

    #define SMC(S, P0, P1) { \
        float e_[16]; \
        _Pragma("unroll") \
        for (int r = 0; r < 16; ++r) e_[r] = __builtin_amdgcn_exp2f(S[r]); \
        float s_ = 0.f; \
        _Pragma("unroll") \
        for (int r = 0; r < 16; r += 4) s_ += (e_[r] + e_[r+1]) + (e_[r+2] + e_[r+3]); \
        ssum += s_; \
        unsigned a_[8]; \
        _Pragma("unroll") \
        for (int i = 0; i < 8; ++i) a_[i] = pkbf(e_[2*i], e_[2*i+1]); \
        { unsigned w0_ = a_[0], w1_ = a_[1], w2_ = a_[2], w3_ = a_[3]; \
          asm volatile("v_permlane32_swap_b32 %0, %1" : "+v"(w0_), "+v"(w2_)); \
          asm volatile("v_permlane32_swap_b32 %0, %1" : "+v"(w1_), "+v"(w3_)); \
          P0 = (u32x4){w0_, w1_, w2_, w3_}; } \
        { unsigned w0_ = a_[4], w1_ = a_[5], w2_ = a_[6], w3_ = a_[7]; \
          asm volatile("v_permlane32_swap_b32 %0, %1" : "+v"(w0_), "+v"(w2_)); \
          asm volatile("v_permlane32_swap_b32 %0, %1" : "+v"(w1_), "+v"(w3_)); \
          P1 = (u32x4){w0_, w1_, w2_, w3_}; } }

    #define PVC(kbv, P0, P1, OA) { \
        const bf16x8 pf0_ = __builtin_bit_cast(bf16x8, P0); \
        const bf16x8 vf0_ = *(const bf16x8*)&VBb[lq * 128 + ((((kbv) >> 3) + hi    ) ^ (lq & 7)) * 8]; \
        const bf16x8 pf1_ = __builtin_bit_cast(bf16x8, P1); \
        const bf16x8 vf1_ = *(const bf16x8*)&VBb[lq * 128 + ((((kbv) >> 3) + 2 + hi) ^ (lq & 7)) * 8]; \
        __builtin_amdgcn_s_setprio(1); \
        OA = __builtin_amdgcn_mfma_f32_32x32x16_bf16(vf0_, pf0_, OA, 0, 0, 0); \
        OA = __builtin_amdgcn_mfma_f32_32x32x16_bf16(vf1_, pf1_, OA, 0, 0, 0); \
        __builtin_amdgcn_s_setprio(0); }

    const int NT = LL / 128;   // 16
    for (int it = 0; it < NT; ++it) {
        const int buf = it & 1;
        BARRIER()
        if (it + 1 < NT) { WRITEBUF(buf ^ 1) }
        if (it + 2 < NT) { LOADREGS((it + 2) * 128) }

        const __bf16* KBb = KB[buf];
        const __bf16* VBb = VB[buf];

        f32x16 S0, S1;
        u32x4 Pa, Pb;
        QKC(0,  S0)
        QKC(32, S1)
        SMC(S0, Pa, Pb)
        PVC(0,  Pa, Pb, O0)
        QKC(64, S0)
        SMC(S1, Pa, Pb)
        PVC(32, Pa, Pb, O1)
        QKC(96, S1)
        SMC(S0, Pa, Pb)
        PVC(64, Pa, Pb, O0)
        SMC(S1, Pa, Pb)
        PVC(96, Pa, Pb, O1)
    }
    #undef LOADREGS
    #undef WRITEBUF
    #undef BARRIER
    #undef QKC
    #undef SMC
    #undef PVC

    ssum += __shfl_xor(ssum, 32);
    const float inv = 1.f / ssum;

    __bf16* arow = aT + ((size_t)(b * LL) + q0 + lq) * CC + h * DD;
    #pragma unroll
    for (int gi = 0; gi < 4; ++gi) {
        bf16x4 ov;
        #pragma unroll
        for (int r = 0; r < 4; ++r) ov[r] = (__bf16)((O0[4*gi + r] + O1[4*gi + r]) * inv);
        *(bf16x4*)&arow[8 * gi + 4 * hi] = ov;
    }
}

// ---------------------------------------------------------------------------
// outproj (round-6 verified): out fp32 [b][c][l] = wo . a + bo + q.
// tile 64 o x 64 l, grid (32,4,4) block 256 (4 waves, 2Mx2N).
// ---------------------------------------------------------------------------
__global__ __launch_bounds__(256) void outproj_kernel(
    const float* __restrict__ W, const __bf16* __restrict__ X,
    const float* __restrict__ bias, const float* __restrict__ resid,
    float* __restrict__ outF)
{
    __shared__ __align__(16) __bf16 Wl[64][136];
    __shared__ __align__(16) __bf16 Xl[64][136];

    const int lt = blockIdx.x * 64;
    const int ot = blockIdx.y * 64;
    const int b  = blockIdx.z;
    const int t  = threadIdx.x;
    const int wvi = t >> 6;
    const int wm = wvi >> 1;
    const int wn = wvi & 1;
    const int l  = t & 63;
    const int lq = l & 15;
    const int g  = l >> 4;

    f32x4 acc[2][2];
    #pragma unroll
    for (int mi = 0; mi < 2; ++mi)
        #pragma unroll
        for (int ni = 0; ni < 2; ++ni) acc[mi][ni] = (f32x4){0.f,0.f,0.f,0.f};

    for (int ks = 0; ks < 2; ++ks) {
        __syncthreads();
        #pragma unroll
        for (int i = 0; i < 8; ++i) {
            const int idx = i * 256 + t;
            const int row = idx >> 5;
            const int ch  = idx & 31;
            const float4 w4 = *(const float4*)&W[(size_t)(ot + row) * CC + ks * 128 + ch * 4];
            bf16x4 wb;
            wb[0] = (__bf16)w4.x; wb[1] = (__bf16)w4.y;
            wb[2] = (__bf16)w4.z; wb[3] = (__bf16)w4.w;
            *(bf16x4*)&Wl[row][ch * 4] = wb;
        }
        #pragma unroll
        for (int i = 0; i < 4; ++i) {
            const int idx = i * 256 + t;
            const int row = idx >> 4, ch = idx & 15;
            *(bf16x8*)&Xl[row][ch * 8] =
                *(const bf16x8*)&X[(size_t)(b * LL + lt + row) * CC + ks * 128 + ch * 8];
        }
        __syncthreads();

        #pragma unroll
        for (int kk = 0; kk < 4; ++kk) {
            bf16x8 af[2], bfr[2];
            #pragma unroll
            for (int mi = 0; mi < 2; ++mi)
                af[mi] = *(const bf16x8*)&Wl[wm * 32 + mi * 16 + lq][kk * 32 + g * 8];
            #pragma unroll
            for (int ni = 0; ni < 2; ++ni)
                bfr[ni] = *(const bf16x8*)&Xl[wn * 32 + ni * 16 + lq][kk * 32 + g * 8];
            #pragma unroll
            for (int mi = 0; mi < 2; ++mi)
                #pragma unroll
                for (int ni = 0; ni < 2; ++ni)
                    acc[mi][ni] = __builtin_amdgcn_mfma_f32_16x16x32_bf16(
                        af[mi], bfr[ni], acc[mi][ni], 0, 0, 0);
        }
    }

    #pragma unroll
    for (int mi = 0; mi < 2; ++mi) {
        const float4 b4 = *(const float4*)&bias[ot + wm * 32 + mi * 16 + g * 4];
        const float bb[4] = {b4.x, b4.y, b4.z, b4.w};
        #pragma unroll
        for (int ni = 0; ni < 2; ++ni) {
            const int col = lt + wn * 32 + ni * 16 + lq;
            #pragma unroll
            for (int r = 0; r < 4; ++r) {
                const int o = ot + wm * 32 + mi * 16 + g * 4 + r;
                const size_t a = (size_t)(b * CC + o) * LL + col;
                outF[a] = acc[mi][ni][r] + bb[r] + resid[a];
            }
        }
    }
}

// ---------------------------------------------------------------------------
extern "C" void kernel_launch(void* const* d_in, const int* in_sizes, int n_in,
                              void* d_out, int out_size, void* d_ws, size_t ws_size,
                              hipStream_t stream)
{
    const float* v     = (const float*)d_in[0];
    const float* k     = (const float*)d_in[1];
    const float* q     = (const float*)d_in[2];
    const float* pe_q  = (const float*)d_in[3];
    const float* pe_vk = (const float*)d_in[4];
    const float* wq    = (const float*)d_in[5];
    const float* bq    = (const float*)d_in[6];
    const float* gq    = (const float*)d_in[7];
    const float* betaq = (const float*)d_in[8];
    const float* mq    = (const float*)d_in[9];
    const float* varq  = (const float*)d_in[10];
    const float* wk    = (const float*)d_in[11];
    const float* bk    = (const float*)d_in[12];
    const float* gk    = (const float*)d_in[13];
    const float* betak = (const float*)d_in[14];
    const float* mk    = (const float*)d_in[15];
    const float* vark  = (const float*)d_in[16];
    const float* wv    = (const float*)d_in[17];
    const float* bv    = (const float*)d_in[18];
    const float* gv    = (const float*)d_in[19];
    const float* betav = (const float*)d_in[20];
    const float* mv    = (const float*)d_in[21];
    const float* varv  = (const float*)d_in[22];
    const float* wo    = (const float*)d_in[23];
    const float* bo    = (const float*)d_in[24];

    float* out = (float*)d_out;

    const size_t E = (size_t)BB * CC * LL;   // 2,097,152
    __bf16* qT  = (__bf16*)d_ws;
    __bf16* kT  = qT + E;
    __bf16* vN  = kT + E;
    __bf16* aT  = vN + E;

    const float qscale = 0.17677669529663687f * 1.4426950408889634f; // 1/sqrt(32)*log2e

    hipLaunchKernelGGL(qkv_gemm_kernel, dim3(16, 4, 12), dim3(512), 0, stream,
                       q, k, v, pe_q, pe_vk,
                       wq, bq, gq, betaq, mq, varq,
                       wk, bk, gk, betak, mk, vark,
                       wv, bv, gv, betav, mv, varv,
                       qT, kT, vN, qscale);

    hipLaunchKernelGGL(attn_mfma_kernel, dim3(8, HH, BB), dim3(512), 0, stream,
                       qT, kT, vN, aT);

    hipLaunchKernelGGL(outproj_kernel, dim3(32, 4, 4), dim3(256), 0, stream,
                       wo, aT, bo, q, out);
}